// Round 21
// baseline (129.454 us; speedup 1.0000x reference)
//
#include <hip/hip_runtime.h>

typedef __attribute__((ext_vector_type(8))) __bf16 bf16x8;
typedef __attribute__((ext_vector_type(4))) __bf16 bf16x4;
typedef __attribute__((ext_vector_type(4))) float f32x4;
typedef __attribute__((ext_vector_type(16))) float f32x16;
typedef __attribute__((ext_vector_type(8))) unsigned short us8;
typedef __attribute__((ext_vector_type(4))) unsigned int u32x4;

constexpr float SCALE_L2E = 0.08838834764831845f * 1.4426950408889634f; // (1/sqrt(128))*log2(e)

__device__ __forceinline__ unsigned short f2bf(float f) {
  unsigned int u = __float_as_uint(f);
  u = (u + 0x7FFFu + ((u >> 16) & 1u)) >> 16;
  return (unsigned short)u;
}

__device__ __forceinline__ void gl_lds16(const void* g, void* l) {
  __builtin_amdgcn_global_load_lds(
      (__attribute__((address_space(1))) void*)const_cast<void*>(g),
      (__attribute__((address_space(3))) void*)l, 16, 0, 0);
}

// ---------------- K0: f32 -> bf16 convert (query + 3 weight matrices) ----------------
__global__ __launch_bounds__(256) void k_convert(
    const float* __restrict__ q, const float* __restrict__ wq,
    const float* __restrict__ wk, const float* __restrict__ wv,
    unsigned short* __restrict__ xb, unsigned short* __restrict__ wb) {
  long i = ((long)blockIdx.x * 256 + threadIdx.x) * 8;
  const float* s; unsigned short* d;
  if (i < 4194304)      { s = q  + i;             d = xb + i; }
  else if (i < 5242880) { s = wq + (i - 4194304); d = wb + (i - 4194304); }
  else if (i < 6291456) { s = wk + (i - 5242880); d = wb + 1048576 + (i - 5242880); }
  else                  { s = wv + (i - 6291456); d = wb + 2097152 + (i - 6291456); }
  float4 a = *(const float4*)s;
  float4 b = *(const float4*)(s + 4);
  us8 r;
  r[0]=f2bf(a.x); r[1]=f2bf(a.y); r[2]=f2bf(a.z); r[3]=f2bf(a.w);
  r[4]=f2bf(b.x); r[5]=f2bf(b.y); r[6]=f2bf(b.z); r[7]=f2bf(b.w);
  *(us8*)d = r;
}

// ---------------- K1: projection GEMM  C = X @ W^T + b  (z selects q/k/v) ----------------
// z==0 (q): sign twist, row-major. z==1 (k): row-major (repacked). z==2 (v): vfrag order.
__global__ __launch_bounds__(256) void k_proj(
    const unsigned short* __restrict__ xb, const unsigned short* __restrict__ wb,
    const float* __restrict__ bq, const float* __restrict__ bk, const float* __restrict__ bv,
    unsigned short* __restrict__ oq, unsigned short* __restrict__ ok_, unsigned short* __restrict__ vt) {
  __shared__ unsigned short As[4096]; // 128 rows x 32 k
  __shared__ unsigned short Bs[4096];
  const int t = threadIdx.x;
  const int wave = t >> 6, lane = t & 63;
  const int lrow = lane & 15, grp = lane >> 4;
  const int z = blockIdx.z;
  const unsigned short* w = wb + (size_t)z * 1048576;
  const float* bias = (z == 0) ? bq : ((z == 1) ? bk : bv);

  const unsigned short* asrc = xb + ((size_t)(blockIdx.y * 128 + (t >> 2)) * 1024 + (t & 3) * 8);
  const unsigned short* bsrc = w  + ((size_t)(blockIdx.x * 128 + (t >> 2)) * 1024 + (t & 3) * 8);

  f32x4 acc[4][4] = {};
  for (int kt = 0; kt < 32; ++kt) {
    gl_lds16(asrc + kt*32,              &As[t*8]);
    gl_lds16(asrc + kt*32 + 64*1024,    &As[2048 + t*8]);
    gl_lds16(bsrc + kt*32,              &Bs[t*8]);
    gl_lds16(bsrc + kt*32 + 64*1024,    &Bs[2048 + t*8]);
    __syncthreads();
    const int wr = wave >> 1, wc = wave & 1;
    bf16x8 af[4], bf[4];
#pragma unroll
    for (int mf = 0; mf < 4; ++mf)
      af[mf] = *(const bf16x8*)&As[(wr*64 + mf*16 + lrow)*32 + grp*8];
#pragma unroll
    for (int nf = 0; nf < 4; ++nf)
      bf[nf] = *(const bf16x8*)&Bs[(wc*64 + nf*16 + lrow)*32 + grp*8];
#pragma unroll
    for (int mf = 0; mf < 4; ++mf)
#pragma unroll
      for (int nf = 0; nf < 4; ++nf)
        acc[mf][nf] = __builtin_amdgcn_mfma_f32_16x16x32_bf16(af[mf], bf[nf], acc[mf][nf], 0, 0, 0);
    __syncthreads();
  }
  const int wr = wave >> 1, wc = wave & 1;
  if (z == 2) {
#pragma unroll
    for (int nf = 0; nf < 4; ++nf) {
      const int col = blockIdx.x*128 + wc*64 + nf*16 + lrow;   // global channel (h,d)
      const int h = col >> 7, dd = col & 127;
      const int dt = dd >> 5, lv = dd & 31;
      const float bsv = bias[col];
#pragma unroll
      for (int mf = 0; mf < 4; ++mf) {
        const int r0 = blockIdx.y*128 + wr*64 + mf*16 + grp*4;
        const int bb = r0 >> 11, m = r0 & 2047;
        const int mc = m >> 4, him = (m >> 3) & 1, j0 = m & 7;
        bf16x4 pv;
#pragma unroll
        for (int i = 0; i < 4; ++i) pv[i] = (__bf16)(acc[mf][nf][i] + bsv);
        const size_t off = ((((size_t)((bb*8 + h)*4 + dt))*128 + mc)*64 + lv + 32*him)*8 + j0;
        *(bf16x4*)&vt[off] = pv;
      }
    }
  } else {
    unsigned short* dst = (z == 0) ? oq : ok_;
    const float sign = (z == 0 && (lane & 7) >= 4) ? -1.0f : 1.0f;
#pragma unroll
    for (int nf = 0; nf < 4; ++nf) {
      const int col = blockIdx.x*128 + wc*64 + nf*16 + lrow;
      const float bsv = bias[col];
#pragma unroll
      for (int mf = 0; mf < 4; ++mf)
#pragma unroll
        for (int i = 0; i < 4; ++i) {
          const int row = blockIdx.y*128 + wr*64 + mf*16 + grp*4 + i;
          dst[(size_t)row*1024 + col] = f2bf((acc[mf][nf][i] + bsv) * sign);
        }
    }
  }
}

// ---------------- K2: repack row-major -> 32x32 fragment order (both K and Q, one launch) ----------------
// frag[bh][tile32][kc][lane][j]: lane=(r&31)+32*((k>>3)&1), j=k&7.
__global__ __launch_bounds__(256) void k_repack2(
    const unsigned short* __restrict__ kws, unsigned short* __restrict__ kfrag,
    const unsigned short* __restrict__ qws, unsigned short* __restrict__ qfrag) {
  const int g = blockIdx.x * 256 + threadIdx.x;   // 0..1048575
  const int c = g & 524287;
  const unsigned short* src = (g < 524288) ? kws : qws;
  unsigned short* frag = (g < 524288) ? kfrag : qfrag;
  const int lane = c & 63, kc = (c >> 6) & 7, mtile = (c >> 9) & 63, bh = c >> 15;
  const int b = bh >> 3, h = bh & 7;
  const int m = mtile*32 + (lane & 31);
  const int kd = kc*16 + (lane >> 5)*8;
  us8 v = *(const us8*)&src[((size_t)(b*2048 + m))*1024 + h*128 + kd];
  *(us8*)&frag[(size_t)c * 8] = v;
}

// ---------------- K3: fused attention out + rowsum (round-17 verified: QBLK=128, 2/CU) ----------------
__global__ __launch_bounds__(512) void k_attn_out(
    const unsigned short* __restrict__ qw, const unsigned short* __restrict__ kfrag,
    const unsigned short* __restrict__ vfrag, float* __restrict__ outp,
    float* __restrict__ rsw) {
  __shared__ __align__(16) char pool[65536];
  unsigned short (*KsL)[8192] = (unsigned short(*)[8192])pool;             // [2][8192] us, 32 KB
  unsigned short (*VsL)[8192] = (unsigned short(*)[8192])(pool + 32768);   // [2][8192] us, 32 KB
  float (*slab)[32][36] = (float(*)[32][36])pool;                          // 36.9 KB overlay (post-loop)
  float (*rsred)[32] = (float(*)[32])(pool + 40960);                       // [8][32] overlay
  float* invb = (float*)(pool + 45056);                                    // [128] overlay

  const int bid = blockIdx.x;
  const int xcd = bid & 7, r_ = bid >> 3;
  const int bh = (xcd << 1) | (r_ & 1);    // 2 bh per XCD -> K/V L2-resident
  const int lt = r_ >> 1;                  // 0..15 (128-l tile)
  const int b = bh >> 3, h = bh & 7;
  const int t = threadIdx.x;
  const int wave = t >> 6, lane = t & 63;
  const int mg = wave >> 2, lg = wave & 3;
  const int lm = lane & 31, hi = lane >> 5;

  bf16x8 qf[8];
  {
    const unsigned short* qp = qw + ((size_t)(b*2048 + lt*128 + lg*32 + lm))*1024
                                  + (size_t)h*128 + hi*8;
#pragma unroll
    for (int kc = 0; kc < 8; ++kc) qf[kc] = *(const bf16x8*)(qp + kc*16);
  }

  const unsigned short* kbp = kfrag + (size_t)bh*262144;
  const unsigned short* vbp = vfrag + (size_t)bh*262144;
  const int vdt = (t >> 6) & 3, vw2 = (t >> 8) & 1, vi8 = (t & 63) * 8;

  auto STAGE = [&](int buf, int it) {
#pragma unroll
    for (int q = 0; q < 2; ++q)
      gl_lds16(kbp + (q*32 + it)*4096 + t*8, &KsL[buf][q*4096 + t*8]);
#pragma unroll
    for (int r = 0; r < 2; ++r)
      gl_lds16(vbp + vdt*65536 + (r*64 + it*2 + vw2)*512 + vi8, &VsL[buf][r*4096 + t*8]);
  };

  f32x16 oacc[4] = {};
  float rs = 0.f;

  STAGE(0, 0);
  __syncthreads();

  for (int it = 0; it < 32; ++it) {
    const int cur = it & 1;
    if (it + 1 < 32) STAGE(cur ^ 1, it + 1);

    bf16x8 kf[8];
#pragma unroll
    for (int kc = 0; kc < 8; ++kc)
      kf[kc] = *(const bf16x8*)&KsL[cur][mg*4096 + kc*512 + lane*8];
    f32x16 s = {};
#pragma unroll
    for (int kc = 0; kc < 8; ++kc)
      s = __builtin_amdgcn_mfma_f32_32x32x16_bf16(kf[kc], qf[kc], s, 0, 0, 0);

    bf16x8 vf[8];
#pragma unroll
    for (int w2 = 0; w2 < 2; ++w2)
#pragma unroll
      for (int dt = 0; dt < 4; ++dt)
        vf[w2*4 + dt] = *(const bf16x8*)&VsL[cur][(mg*8 + w2*4 + dt)*512 + lane*8];

    float e[16];
#pragma unroll
    for (int r = 0; r < 16; ++r) e[r] = __builtin_amdgcn_exp2f(s[r] * SCALE_L2E);
    float ps = 0.f;
#pragma unroll
    for (int r = 0; r < 16; ++r) ps += e[r];
    rs += ps;

    bf16x8 pf[2];
#pragma unroll
    for (int w2 = 0; w2 < 2; ++w2) {
      unsigned a0, a1, b0, b1;
      asm("v_cvt_pk_bf16_f32 %0, %1, %2" : "=v"(a0) : "v"(e[8*w2+0]), "v"(e[8*w2+1]));
      asm("v_cvt_pk_bf16_f32 %0, %1, %2" : "=v"(a1) : "v"(e[8*w2+2]), "v"(e[8*w2+3]));
      asm("v_cvt_pk_bf16_f32 %0, %1, %2" : "=v"(b0) : "v"(e[8*w2+4]), "v"(e[8*w2+5]));
      asm("v_cvt_pk_bf16_f32 %0, %1, %2" : "=v"(b1) : "v"(e[8*w2+6]), "v"(e[8*w2+7]));
      asm("v_permlane32_swap_b32 %0, %1" : "+v"(a0), "+v"(b0));
      asm("v_permlane32_swap_b32 %0, %1" : "+v"(a1), "+v"(b1));
      u32x4 pw = {a0, a1, b0, b1};
      pf[w2] = __builtin_bit_cast(bf16x8, pw);
    }

#pragma unroll
    for (int dt = 0; dt < 4; ++dt) {
      oacc[dt] = __builtin_amdgcn_mfma_f32_32x32x16_bf16(vf[dt],     pf[0], oacc[dt], 0, 0, 0);
      oacc[dt] = __builtin_amdgcn_mfma_f32_32x32x16_bf16(vf[4 + dt], pf[1], oacc[dt], 0, 0, 0);
    }
    __syncthreads();
  }

  rs += __shfl_xor(rs, 32, 64);
  if (lane < 32) rsred[wave][lm] = rs;
  __syncthreads();
  if (t < 128) {
    const int tlg = t >> 5, tl = t & 31;
    const float tot = rsred[tlg][tl] + rsred[4 + tlg][tl];
    rsw[(size_t)bh*2048 + lt*128 + t] = tot;
    invb[t] = 1.0f / tot;
  }

#pragma unroll
  for (int dt = 0; dt < 4; ++dt) {
    __syncthreads();
#pragma unroll
    for (int c = 0; c < 4; ++c) {
      float4 v4 = { oacc[dt][4*c + 0], oacc[dt][4*c + 1], oacc[dt][4*c + 2], oacc[dt][4*c + 3] };
      *(float4*)&slab[wave][lm][8*c + 4*hi] = v4;
    }
    __syncthreads();
    const int tlg = t >> 7, idx = t & 127;
    const int l = idx >> 2, d0 = (idx & 3) * 8;
    const float iv = invb[tlg*32 + l];
    float4 x0 = *(const float4*)&slab[tlg][l][d0];
    float4 x1 = *(const float4*)&slab[tlg][l][d0 + 4];
    float4 y0 = *(const float4*)&slab[4 + tlg][l][d0];
    float4 y1 = *(const float4*)&slab[4 + tlg][l][d0 + 4];
    float4 o0 = { (x0.x + y0.x)*iv, (x0.y + y0.y)*iv, (x0.z + y0.z)*iv, (x0.w + y0.w)*iv };
    float4 o1 = { (x1.x + y1.x)*iv, (x1.y + y1.y)*iv, (x1.z + y1.z)*iv, (x1.w + y1.w)*iv };
    float* op = outp + ((size_t)(b*2048 + lt*128 + tlg*32 + l))*1024 + h*128 + dt*32 + d0;
    *(float4*)op = o0;
    *(float4*)(op + 4) = o1;
  }
}

// ---------------- K4 v7: head-mean, register h-sum, 2x2 wave tiling (L1 dedup) ----------------
// v5 math byte-identical; block now covers 64l x 64m with waves as (wl,wm) 2x2:
// each Q tile read by 2 waves, each K chunk by 2 waves -> unique L2 bytes/block-h
// 40KB -> 32KB (-20%). Same grid (2048), barrier-free, XCD m-range ownership kept.
__global__ __launch_bounds__(256) void k_attn_mean(
    const unsigned short* __restrict__ qfrag, const unsigned short* __restrict__ kfrag,
    const float* __restrict__ rsw, float* __restrict__ meanp) {
  __shared__ float inv_s[512];   // [h][64 l]
  const int u = blockIdx.x;
  const int xcd = u & 7, s_ = u >> 3;        // s_ 0..255
  const int m64 = xcd*4 + (s_ & 3);          // 64-m chunk 0..31 (XCD owns 4)
  const int lt64 = (s_ >> 2) & 31;           // 64-l tile 0..31
  const int b  = s_ >> 7;                    // 0..1
  const int t = threadIdx.x;
  const int wave = t >> 6, lane = t & 63;
  const int wl = wave >> 1, wm = wave & 1;
  const int lt = lt64*2 + wl;                // 32-l tile
  const int mc = m64*2 + wm;                 // 32-m chunk
  const int lm = lane & 31, hi = lane >> 5;

  for (int idx = t; idx < 512; idx += 256) {
    const int hh = idx >> 6, ll = idx & 63;
    inv_s[idx] = 1.0f / rsw[(size_t)(b*8 + hh)*2048 + lt64*64 + ll];
  }
  __syncthreads();

  float acc[16] = {};
  for (int h = 0; h < 8; ++h) {
    const int bh = b*8 + h;
    const unsigned short* qp = qfrag + (size_t)(bh*64 + lt)*4096 + lane*8;
    const unsigned short* kp = kfrag + (size_t)(bh*64 + mc)*4096 + lane*8;
    bf16x8 qf[8], kf[8];
#pragma unroll
    for (int kc = 0; kc < 8; ++kc) {
      qf[kc] = *(const bf16x8*)(qp + kc*512);
      kf[kc] = *(const bf16x8*)(kp + kc*512);
    }
    f32x16 s = {};
#pragma unroll
    for (int kc = 0; kc < 8; ++kc)
      s = __builtin_amdgcn_mfma_f32_32x32x16_bf16(qf[kc], kf[kc], s, 0, 0, 0);
#pragma unroll
    for (int rq = 0; rq < 4; ++rq) {
      f32x4 ivq = *(const f32x4*)&inv_s[h*64 + wl*32 + rq*8 + hi*4];
#pragma unroll
      for (int j = 0; j < 4; ++j)
        acc[rq*4 + j] += __builtin_amdgcn_exp2f(s[rq*4 + j] * SCALE_L2E) * ivq[j];
    }
  }
#pragma unroll
  for (int r = 0; r < 16; ++r) {
    const int l = lt*32 + (r & 3) + 8*(r >> 2) + 4*hi;
    meanp[((size_t)(b*2048 + l))*2048 + mc*32 + lm] = acc[r] * 0.125f;
  }
}

extern "C" void kernel_launch(void* const* d_in, const int* in_sizes, int n_in,
                              void* d_out, int out_size, void* d_ws, size_t ws_size,
                              hipStream_t stream) {
  (void)in_sizes; (void)n_in; (void)out_size; (void)ws_size;
  const float* query = (const float*)d_in[0];
  const float* Wq = (const float*)d_in[1];
  const float* bq = (const float*)d_in[2];
  const float* Wk = (const float*)d_in[3];
  const float* bk = (const float*)d_in[4];
  const float* Wv = (const float*)d_in[5];
  const float* bv = (const float*)d_in[6];
  float* outp  = (float*)d_out;
  float* meanp = outp + 4194304;           // (B,L,DM) then (B,L,L)

  char* ws = (char*)d_ws;
  unsigned short* xb    = (unsigned short*)(ws);              // 8.4 MB
  unsigned short* wb    = (unsigned short*)(ws + 8388608);    // 6.3 MB (Wq,Wk,Wv)
  unsigned short* qws   = (unsigned short*)(ws + 14680064);   // 8.4 MB (sign-twisted q, row-major)
  unsigned short* kws   = (unsigned short*)(ws + 23068672);   // 8.4 MB (k row-major, repack input)
  unsigned short* kfrag = (unsigned short*)(ws + 31457280);   // 8.4 MB (k frag-order)
  unsigned short* vfrag = (unsigned short*)(ws + 39845888);   // 8.4 MB (v frag-order)
  float*          rsw   = (float*)(ws + 48234496);            // 128 KB rowsums
  unsigned short* qfrag = (unsigned short*)(ws + 48365568);   // 8.4 MB (q frag-order)

  k_convert<<<3584, 256, 0, stream>>>(query, Wq, Wk, Wv, xb, wb);
  k_proj<<<dim3(8, 32, 3), 256, 0, stream>>>(xb, wb, bq, bk, bv, qws, kws, vfrag);
  k_repack2<<<4096, 256, 0, stream>>>(kws, kfrag, qws, qfrag);
  k_attn_out<<<256, 512, 0, stream>>>(qws, kfrag, vfrag, outp, rsw);
  k_attn_mean<<<2048, 256, 0, stream>>>(qfrag, kfrag, rsw, meanp);
}

// Round 22
// 128.184 us; speedup vs baseline: 1.0099x; 1.0099x over previous
//
#include <hip/hip_runtime.h>

typedef __attribute__((ext_vector_type(8))) __bf16 bf16x8;
typedef __attribute__((ext_vector_type(4))) __bf16 bf16x4;
typedef __attribute__((ext_vector_type(4))) float f32x4;
typedef __attribute__((ext_vector_type(16))) float f32x16;
typedef __attribute__((ext_vector_type(8))) unsigned short us8;
typedef __attribute__((ext_vector_type(4))) unsigned int u32x4;

constexpr float SCALE_L2E = 0.08838834764831845f * 1.4426950408889634f; // (1/sqrt(128))*log2(e)

__device__ __forceinline__ unsigned short f2bf(float f) {
  unsigned int u = __float_as_uint(f);
  u = (u + 0x7FFFu + ((u >> 16) & 1u)) >> 16;
  return (unsigned short)u;
}

__device__ __forceinline__ void gl_lds16(const void* g, void* l) {
  __builtin_amdgcn_global_load_lds(
      (__attribute__((address_space(1))) void*)const_cast<void*>(g),
      (__attribute__((address_space(3))) void*)l, 16, 0, 0);
}

// ---------------- K0: f32 -> bf16 convert (query + 3 weight matrices) ----------------
__global__ __launch_bounds__(256) void k_convert(
    const float* __restrict__ q, const float* __restrict__ wq,
    const float* __restrict__ wk, const float* __restrict__ wv,
    unsigned short* __restrict__ xb, unsigned short* __restrict__ wb) {
  long i = ((long)blockIdx.x * 256 + threadIdx.x) * 8;
  const float* s; unsigned short* d;
  if (i < 4194304)      { s = q  + i;             d = xb + i; }
  else if (i < 5242880) { s = wq + (i - 4194304); d = wb + (i - 4194304); }
  else if (i < 6291456) { s = wk + (i - 5242880); d = wb + 1048576 + (i - 5242880); }
  else                  { s = wv + (i - 6291456); d = wb + 2097152 + (i - 6291456); }
  float4 a = *(const float4*)s;
  float4 b = *(const float4*)(s + 4);
  us8 r;
  r[0]=f2bf(a.x); r[1]=f2bf(a.y); r[2]=f2bf(a.z); r[3]=f2bf(a.w);
  r[4]=f2bf(b.x); r[5]=f2bf(b.y); r[6]=f2bf(b.z); r[7]=f2bf(b.w);
  *(us8*)d = r;
}

// ---------------- K1: projection GEMM  C = X @ W^T + b  (z selects q/k/v) ----------------
// z==0 (q): sign twist, row-major. z==1 (k): row-major (repacked). z==2 (v): vfrag order.
__global__ __launch_bounds__(256) void k_proj(
    const unsigned short* __restrict__ xb, const unsigned short* __restrict__ wb,
    const float* __restrict__ bq, const float* __restrict__ bk, const float* __restrict__ bv,
    unsigned short* __restrict__ oq, unsigned short* __restrict__ ok_, unsigned short* __restrict__ vt) {
  __shared__ unsigned short As[4096]; // 128 rows x 32 k
  __shared__ unsigned short Bs[4096];
  const int t = threadIdx.x;
  const int wave = t >> 6, lane = t & 63;
  const int lrow = lane & 15, grp = lane >> 4;
  const int z = blockIdx.z;
  const unsigned short* w = wb + (size_t)z * 1048576;
  const float* bias = (z == 0) ? bq : ((z == 1) ? bk : bv);

  const unsigned short* asrc = xb + ((size_t)(blockIdx.y * 128 + (t >> 2)) * 1024 + (t & 3) * 8);
  const unsigned short* bsrc = w  + ((size_t)(blockIdx.x * 128 + (t >> 2)) * 1024 + (t & 3) * 8);

  f32x4 acc[4][4] = {};
  for (int kt = 0; kt < 32; ++kt) {
    gl_lds16(asrc + kt*32,              &As[t*8]);
    gl_lds16(asrc + kt*32 + 64*1024,    &As[2048 + t*8]);
    gl_lds16(bsrc + kt*32,              &Bs[t*8]);
    gl_lds16(bsrc + kt*32 + 64*1024,    &Bs[2048 + t*8]);
    __syncthreads();
    const int wr = wave >> 1, wc = wave & 1;
    bf16x8 af[4], bf[4];
#pragma unroll
    for (int mf = 0; mf < 4; ++mf)
      af[mf] = *(const bf16x8*)&As[(wr*64 + mf*16 + lrow)*32 + grp*8];
#pragma unroll
    for (int nf = 0; nf < 4; ++nf)
      bf[nf] = *(const bf16x8*)&Bs[(wc*64 + nf*16 + lrow)*32 + grp*8];
#pragma unroll
    for (int mf = 0; mf < 4; ++mf)
#pragma unroll
      for (int nf = 0; nf < 4; ++nf)
        acc[mf][nf] = __builtin_amdgcn_mfma_f32_16x16x32_bf16(af[mf], bf[nf], acc[mf][nf], 0, 0, 0);
    __syncthreads();
  }
  const int wr = wave >> 1, wc = wave & 1;
  if (z == 2) {
#pragma unroll
    for (int nf = 0; nf < 4; ++nf) {
      const int col = blockIdx.x*128 + wc*64 + nf*16 + lrow;   // global channel (h,d)
      const int h = col >> 7, dd = col & 127;
      const int dt = dd >> 5, lv = dd & 31;
      const float bsv = bias[col];
#pragma unroll
      for (int mf = 0; mf < 4; ++mf) {
        const int r0 = blockIdx.y*128 + wr*64 + mf*16 + grp*4;
        const int bb = r0 >> 11, m = r0 & 2047;
        const int mc = m >> 4, him = (m >> 3) & 1, j0 = m & 7;
        bf16x4 pv;
#pragma unroll
        for (int i = 0; i < 4; ++i) pv[i] = (__bf16)(acc[mf][nf][i] + bsv);
        const size_t off = ((((size_t)((bb*8 + h)*4 + dt))*128 + mc)*64 + lv + 32*him)*8 + j0;
        *(bf16x4*)&vt[off] = pv;
      }
    }
  } else {
    unsigned short* dst = (z == 0) ? oq : ok_;
    const float sign = (z == 0 && (lane & 7) >= 4) ? -1.0f : 1.0f;
#pragma unroll
    for (int nf = 0; nf < 4; ++nf) {
      const int col = blockIdx.x*128 + wc*64 + nf*16 + lrow;
      const float bsv = bias[col];
#pragma unroll
      for (int mf = 0; mf < 4; ++mf)
#pragma unroll
        for (int i = 0; i < 4; ++i) {
          const int row = blockIdx.y*128 + wr*64 + mf*16 + grp*4 + i;
          dst[(size_t)row*1024 + col] = f2bf((acc[mf][nf][i] + bsv) * sign);
        }
    }
  }
}

// ---------------- K2: repack row-major -> 32x32 fragment order (both K and Q, one launch) ----------------
// frag[bh][tile32][kc][lane][j]: lane=(r&31)+32*((k>>3)&1), j=k&7.
__global__ __launch_bounds__(256) void k_repack2(
    const unsigned short* __restrict__ kws, unsigned short* __restrict__ kfrag,
    const unsigned short* __restrict__ qws, unsigned short* __restrict__ qfrag) {
  const int g = blockIdx.x * 256 + threadIdx.x;   // 0..1048575
  const int c = g & 524287;
  const unsigned short* src = (g < 524288) ? kws : qws;
  unsigned short* frag = (g < 524288) ? kfrag : qfrag;
  const int lane = c & 63, kc = (c >> 6) & 7, mtile = (c >> 9) & 63, bh = c >> 15;
  const int b = bh >> 3, h = bh & 7;
  const int m = mtile*32 + (lane & 31);
  const int kd = kc*16 + (lane >> 5)*8;
  us8 v = *(const us8*)&src[((size_t)(b*2048 + m))*1024 + h*128 + kd];
  *(us8*)&frag[(size_t)c * 8] = v;
}

// ---------------- K3: fused attention out + rowsum (round-17 verified: QBLK=128, 2/CU) ----------------
__global__ __launch_bounds__(512) void k_attn_out(
    const unsigned short* __restrict__ qw, const unsigned short* __restrict__ kfrag,
    const unsigned short* __restrict__ vfrag, float* __restrict__ outp,
    float* __restrict__ rsw) {
  __shared__ __align__(16) char pool[65536];
  unsigned short (*KsL)[8192] = (unsigned short(*)[8192])pool;             // [2][8192] us, 32 KB
  unsigned short (*VsL)[8192] = (unsigned short(*)[8192])(pool + 32768);   // [2][8192] us, 32 KB
  float (*slab)[32][36] = (float(*)[32][36])pool;                          // 36.9 KB overlay (post-loop)
  float (*rsred)[32] = (float(*)[32])(pool + 40960);                       // [8][32] overlay
  float* invb = (float*)(pool + 45056);                                    // [128] overlay

  const int bid = blockIdx.x;
  const int xcd = bid & 7, r_ = bid >> 3;
  const int bh = (xcd << 1) | (r_ & 1);    // 2 bh per XCD -> K/V L2-resident
  const int lt = r_ >> 1;                  // 0..15 (128-l tile)
  const int b = bh >> 3, h = bh & 7;
  const int t = threadIdx.x;
  const int wave = t >> 6, lane = t & 63;
  const int mg = wave >> 2, lg = wave & 3;
  const int lm = lane & 31, hi = lane >> 5;

  bf16x8 qf[8];
  {
    const unsigned short* qp = qw + ((size_t)(b*2048 + lt*128 + lg*32 + lm))*1024
                                  + (size_t)h*128 + hi*8;
#pragma unroll
    for (int kc = 0; kc < 8; ++kc) qf[kc] = *(const bf16x8*)(qp + kc*16);
  }

  const unsigned short* kbp = kfrag + (size_t)bh*262144;
  const unsigned short* vbp = vfrag + (size_t)bh*262144;
  const int vdt = (t >> 6) & 3, vw2 = (t >> 8) & 1, vi8 = (t & 63) * 8;

  auto STAGE = [&](int buf, int it) {
#pragma unroll
    for (int q = 0; q < 2; ++q)
      gl_lds16(kbp + (q*32 + it)*4096 + t*8, &KsL[buf][q*4096 + t*8]);
#pragma unroll
    for (int r = 0; r < 2; ++r)
      gl_lds16(vbp + vdt*65536 + (r*64 + it*2 + vw2)*512 + vi8, &VsL[buf][r*4096 + t*8]);
  };

  f32x16 oacc[4] = {};
  float rs = 0.f;

  STAGE(0, 0);
  __syncthreads();

  for (int it = 0; it < 32; ++it) {
    const int cur = it & 1;
    if (it + 1 < 32) STAGE(cur ^ 1, it + 1);

    bf16x8 kf[8];
#pragma unroll
    for (int kc = 0; kc < 8; ++kc)
      kf[kc] = *(const bf16x8*)&KsL[cur][mg*4096 + kc*512 + lane*8];
    f32x16 s = {};
#pragma unroll
    for (int kc = 0; kc < 8; ++kc)
      s = __builtin_amdgcn_mfma_f32_32x32x16_bf16(kf[kc], qf[kc], s, 0, 0, 0);

    bf16x8 vf[8];
#pragma unroll
    for (int w2 = 0; w2 < 2; ++w2)
#pragma unroll
      for (int dt = 0; dt < 4; ++dt)
        vf[w2*4 + dt] = *(const bf16x8*)&VsL[cur][(mg*8 + w2*4 + dt)*512 + lane*8];

    float e[16];
#pragma unroll
    for (int r = 0; r < 16; ++r) e[r] = __builtin_amdgcn_exp2f(s[r] * SCALE_L2E);
    float ps = 0.f;
#pragma unroll
    for (int r = 0; r < 16; ++r) ps += e[r];
    rs += ps;

    bf16x8 pf[2];
#pragma unroll
    for (int w2 = 0; w2 < 2; ++w2) {
      unsigned a0, a1, b0, b1;
      asm("v_cvt_pk_bf16_f32 %0, %1, %2" : "=v"(a0) : "v"(e[8*w2+0]), "v"(e[8*w2+1]));
      asm("v_cvt_pk_bf16_f32 %0, %1, %2" : "=v"(a1) : "v"(e[8*w2+2]), "v"(e[8*w2+3]));
      asm("v_cvt_pk_bf16_f32 %0, %1, %2" : "=v"(b0) : "v"(e[8*w2+4]), "v"(e[8*w2+5]));
      asm("v_cvt_pk_bf16_f32 %0, %1, %2" : "=v"(b1) : "v"(e[8*w2+6]), "v"(e[8*w2+7]));
      asm("v_permlane32_swap_b32 %0, %1" : "+v"(a0), "+v"(b0));
      asm("v_permlane32_swap_b32 %0, %1" : "+v"(a1), "+v"(b1));
      u32x4 pw = {a0, a1, b0, b1};
      pf[w2] = __builtin_bit_cast(bf16x8, pw);
    }

#pragma unroll
    for (int dt = 0; dt < 4; ++dt) {
      oacc[dt] = __builtin_amdgcn_mfma_f32_32x32x16_bf16(vf[dt],     pf[0], oacc[dt], 0, 0, 0);
      oacc[dt] = __builtin_amdgcn_mfma_f32_32x32x16_bf16(vf[4 + dt], pf[1], oacc[dt], 0, 0, 0);
    }
    __syncthreads();
  }

  rs += __shfl_xor(rs, 32, 64);
  if (lane < 32) rsred[wave][lm] = rs;
  __syncthreads();
  if (t < 128) {
    const int tlg = t >> 5, tl = t & 31;
    const float tot = rsred[tlg][tl] + rsred[4 + tlg][tl];
    rsw[(size_t)bh*2048 + lt*128 + t] = tot;
    invb[t] = 1.0f / tot;
  }

#pragma unroll
  for (int dt = 0; dt < 4; ++dt) {
    __syncthreads();
#pragma unroll
    for (int c = 0; c < 4; ++c) {
      float4 v4 = { oacc[dt][4*c + 0], oacc[dt][4*c + 1], oacc[dt][4*c + 2], oacc[dt][4*c + 3] };
      *(float4*)&slab[wave][lm][8*c + 4*hi] = v4;
    }
    __syncthreads();
    const int tlg = t >> 7, idx = t & 127;
    const int l = idx >> 2, d0 = (idx & 3) * 8;
    const float iv = invb[tlg*32 + l];
    float4 x0 = *(const float4*)&slab[tlg][l][d0];
    float4 x1 = *(const float4*)&slab[tlg][l][d0 + 4];
    float4 y0 = *(const float4*)&slab[4 + tlg][l][d0];
    float4 y1 = *(const float4*)&slab[4 + tlg][l][d0 + 4];
    float4 o0 = { (x0.x + y0.x)*iv, (x0.y + y0.y)*iv, (x0.z + y0.z)*iv, (x0.w + y0.w)*iv };
    float4 o1 = { (x1.x + y1.x)*iv, (x1.y + y1.y)*iv, (x1.z + y1.z)*iv, (x1.w + y1.w)*iv };
    float* op = outp + ((size_t)(b*2048 + lt*128 + tlg*32 + l))*1024 + h*128 + dt*32 + d0;
    *(float4*)op = o0;
    *(float4*)(op + 4) = o1;
  }
}

// ---------------- K4 v5 (round-18/20 verified, 42.5us): register h-sum, barrier-free ----------------
__global__ __launch_bounds__(256) void k_attn_mean(
    const unsigned short* __restrict__ qfrag, const unsigned short* __restrict__ kfrag,
    const float* __restrict__ rsw, float* __restrict__ meanp) {
  __shared__ float inv_s[256];   // [h][32 l]
  const int u = blockIdx.x;
  const int xcd = u & 7, s_ = u >> 3;        // s_ 0..255
  const int mq = xcd*2 + (s_ & 1);           // m-sixteenth 0..15
  const int lt = (s_ >> 1) & 63;             // 32-l tile 0..63
  const int b  = s_ >> 7;                    // 0..1
  const int t = threadIdx.x;
  const int wave = t >> 6, lane = t & 63;
  const int mc = mq*4 + wave;                // 32-m chunk 0..63
  const int lm = lane & 31, hi = lane >> 5;

  inv_s[t] = 1.0f / rsw[(size_t)(b*8 + (t >> 5))*2048 + lt*32 + (t & 31)];
  __syncthreads();

  float acc[16] = {};
  for (int h = 0; h < 8; ++h) {
    const int bh = b*8 + h;
    const unsigned short* qp = qfrag + (size_t)(bh*64 + lt)*4096 + lane*8;
    const unsigned short* kp = kfrag + (size_t)(bh*64 + mc)*4096 + lane*8;
    bf16x8 qf[8], kf[8];
#pragma unroll
    for (int kc = 0; kc < 8; ++kc) {
      qf[kc] = *(const bf16x8*)(qp + kc*512);
      kf[kc] = *(const bf16x8*)(kp + kc*512);
    }
    f32x16 s = {};
#pragma unroll
    for (int kc = 0; kc < 8; ++kc)
      s = __builtin_amdgcn_mfma_f32_32x32x16_bf16(qf[kc], kf[kc], s, 0, 0, 0);
#pragma unroll
    for (int rq = 0; rq < 4; ++rq) {
      f32x4 ivq = *(const f32x4*)&inv_s[h*32 + rq*8 + hi*4];
#pragma unroll
      for (int j = 0; j < 4; ++j)
        acc[rq*4 + j] += __builtin_amdgcn_exp2f(s[rq*4 + j] * SCALE_L2E) * ivq[j];
    }
  }
#pragma unroll
  for (int r = 0; r < 16; ++r) {
    const int l = lt*32 + (r & 3) + 8*(r >> 2) + 4*hi;
    meanp[((size_t)(b*2048 + l))*2048 + mc*32 + lm] = acc[r] * 0.125f;
  }
}

extern "C" void kernel_launch(void* const* d_in, const int* in_sizes, int n_in,
                              void* d_out, int out_size, void* d_ws, size_t ws_size,
                              hipStream_t stream) {
  (void)in_sizes; (void)n_in; (void)out_size; (void)ws_size;
  const float* query = (const float*)d_in[0];
  const float* Wq = (const float*)d_in[1];
  const float* bq = (const float*)d_in[2];
  const float* Wk = (const float*)d_in[3];
  const float* bk = (const float*)d_in[4];
  const float* Wv = (const float*)d_in[5];
  const float* bv = (const float*)d_in[6];
  float* outp  = (float*)d_out;
  float* meanp = outp + 4194304;           // (B,L,DM) then (B,L,L)

  char* ws = (char*)d_ws;
  unsigned short* xb    = (unsigned short*)(ws);              // 8.4 MB
  unsigned short* wb    = (unsigned short*)(ws + 8388608);    // 6.3 MB (Wq,Wk,Wv)
  unsigned short* qws   = (unsigned short*)(ws + 14680064);   // 8.4 MB (sign-twisted q, row-major)
  unsigned short* kws   = (unsigned short*)(ws + 23068672);   // 8.4 MB (k row-major, repack input)
  unsigned short* kfrag = (unsigned short*)(ws + 31457280);   // 8.4 MB (k frag-order)
  unsigned short* vfrag = (unsigned short*)(ws + 39845888);   // 8.4 MB (v frag-order)
  float*          rsw   = (float*)(ws + 48234496);            // 128 KB rowsums
  unsigned short* qfrag = (unsigned short*)(ws + 48365568);   // 8.4 MB (q frag-order)

  k_convert<<<3584, 256, 0, stream>>>(query, Wq, Wk, Wv, xb, wb);
  k_proj<<<dim3(8, 32, 3), 256, 0, stream>>>(xb, wb, bq, bk, bv, qws, kws, vfrag);
  k_repack2<<<4096, 256, 0, stream>>>(kws, kfrag, qws, qfrag);
  k_attn_out<<<256, 512, 0, stream>>>(qws, kfrag, vfrag, outp, rsw);
  k_attn_mean<<<2048, 256, 0, stream>>>(qfrag, kfrag, rsw, meanp);
}